// Round 1
// baseline (557.179 us; speedup 1.0000x reference)
//
#include <hip/hip_runtime.h>
#include <hip/hip_bf16.h>

// Problem constants (B, T, C, HS) from the reference.
#define NB 256
#define NT 256
#define NC 384
#define NH 64
#define NQ (NB * NT * NH)  // elements per q/k/v tensor = 4194304

__device__ __forceinline__ float bf2f(unsigned short u) {
  union { unsigned int i; float f; } c;
  c.i = ((unsigned int)u) << 16;
  return c.f;
}

__device__ __forceinline__ unsigned short f2bf(float f) {
  union { float f; unsigned int i; } c;
  c.f = f;
  // round-to-nearest-even
  const unsigned int r = c.i + 0x7fffu + ((c.i >> 16) & 1u);
  return (unsigned short)(r >> 16);
}

// ---------------------------------------------------------------------------
// Kernel 1: fused QKV projection.
//   q/k/v[r][h] = sum_c x[r][c] * W{q,k,v}[c][h],  r in [0, B*T), h in [0,64)
// Output stored as bf16 into workspace: [q | k | v], each [B*T][64].
// Block: 256 threads = 8 row-groups x 32 h-pairs; block tile = 128 rows.
// Each thread: 16 rows x 2 cols x 3 matrices = 96 fp32 accumulators.
// x is read exactly once per block (wave-broadcast float4 loads, L2-friendly).
// ---------------------------------------------------------------------------
__global__ __launch_bounds__(256) void qkv_proj_kernel(
    const float* __restrict__ x,
    const float* __restrict__ Wq,
    const float* __restrict__ Wk,
    const float* __restrict__ Wv,
    unsigned short* __restrict__ qkv) {
  const int hp = threadIdx.x & 31;   // h pair index: h = 2*hp, 2*hp+1
  const int g  = threadIdx.x >> 5;   // row group 0..7
  const int row0 = blockIdx.x * 128 + g * 16;

  float aq[16][2], ak[16][2], av[16][2];
#pragma unroll
  for (int i = 0; i < 16; ++i) {
    aq[i][0] = aq[i][1] = 0.f;
    ak[i][0] = ak[i][1] = 0.f;
    av[i][0] = av[i][1] = 0.f;
  }

  const float* xr = x + (size_t)row0 * NC;

  for (int c = 0; c < NC; c += 4) {
    float2 wq[4], wk[4], wv[4];
#pragma unroll
    for (int j = 0; j < 4; ++j) {
      wq[j] = *reinterpret_cast<const float2*>(Wq + (c + j) * NH + hp * 2);
      wk[j] = *reinterpret_cast<const float2*>(Wk + (c + j) * NH + hp * 2);
      wv[j] = *reinterpret_cast<const float2*>(Wv + (c + j) * NH + hp * 2);
    }
#pragma unroll
    for (int i = 0; i < 16; ++i) {
      const float4 xv = *reinterpret_cast<const float4*>(xr + i * NC + c);
      aq[i][0] = fmaf(xv.x, wq[0].x, aq[i][0]);
      aq[i][0] = fmaf(xv.y, wq[1].x, aq[i][0]);
      aq[i][0] = fmaf(xv.z, wq[2].x, aq[i][0]);
      aq[i][0] = fmaf(xv.w, wq[3].x, aq[i][0]);
      aq[i][1] = fmaf(xv.x, wq[0].y, aq[i][1]);
      aq[i][1] = fmaf(xv.y, wq[1].y, aq[i][1]);
      aq[i][1] = fmaf(xv.z, wq[2].y, aq[i][1]);
      aq[i][1] = fmaf(xv.w, wq[3].y, aq[i][1]);

      ak[i][0] = fmaf(xv.x, wk[0].x, ak[i][0]);
      ak[i][0] = fmaf(xv.y, wk[1].x, ak[i][0]);
      ak[i][0] = fmaf(xv.z, wk[2].x, ak[i][0]);
      ak[i][0] = fmaf(xv.w, wk[3].x, ak[i][0]);
      ak[i][1] = fmaf(xv.x, wk[0].y, ak[i][1]);
      ak[i][1] = fmaf(xv.y, wk[1].y, ak[i][1]);
      ak[i][1] = fmaf(xv.z, wk[2].y, ak[i][1]);
      ak[i][1] = fmaf(xv.w, wk[3].y, ak[i][1]);

      av[i][0] = fmaf(xv.x, wv[0].x, av[i][0]);
      av[i][0] = fmaf(xv.y, wv[1].x, av[i][0]);
      av[i][0] = fmaf(xv.z, wv[2].x, av[i][0]);
      av[i][0] = fmaf(xv.w, wv[3].x, av[i][0]);
      av[i][1] = fmaf(xv.x, wv[0].y, av[i][1]);
      av[i][1] = fmaf(xv.y, wv[1].y, av[i][1]);
      av[i][1] = fmaf(xv.z, wv[2].y, av[i][1]);
      av[i][1] = fmaf(xv.w, wv[3].y, av[i][1]);
    }
  }

#pragma unroll
  for (int i = 0; i < 16; ++i) {
    const size_t ro = (size_t)(row0 + i) * NH + hp * 2;
    ushort2 s;
    s.x = f2bf(aq[i][0]); s.y = f2bf(aq[i][1]);
    *reinterpret_cast<ushort2*>(qkv + ro) = s;
    s.x = f2bf(ak[i][0]); s.y = f2bf(ak[i][1]);
    *reinterpret_cast<ushort2*>(qkv + NQ + ro) = s;
    s.x = f2bf(av[i][0]); s.y = f2bf(av[i][1]);
    *reinterpret_cast<ushort2*>(qkv + 2 * NQ + ro) = s;
  }
}

// ---------------------------------------------------------------------------
// Kernel 2: causal attention per batch.
// One block (256 threads) per batch b; thread t owns query row t.
// K, V staged fp32 in LDS (64 KB + 64 KB). Two-pass softmax:
//   pass 1: online scalar max/sum over s <= t
//   pass 2: recompute score, accumulate o[h] += p * v[s][h]
// All LDS reads in the s-loops are same-address across the wave (broadcast,
// conflict-free).
// ---------------------------------------------------------------------------
__global__ __launch_bounds__(256) void attn_kernel(
    const unsigned short* __restrict__ qkv,
    float* __restrict__ out) {
  __shared__ float kls[NT * NH];  // 64 KB
  __shared__ float vls[NT * NH];  // 64 KB

  const int b = blockIdx.x;
  const int t = threadIdx.x;

  const unsigned short* qg = qkv + ((size_t)b * NT + t) * NH;
  const ushort4* ks =
      reinterpret_cast<const ushort4*>(qkv + NQ + (size_t)b * NT * NH);
  const ushort4* vs =
      reinterpret_cast<const ushort4*>(qkv + 2 * NQ + (size_t)b * NT * NH);

  // Stage K and V into LDS (coalesced ushort4 loads, linear float4 stores).
#pragma unroll
  for (int i = 0; i < 16; ++i) {
    const int idx = threadIdx.x + i * 256;  // ushort4 index, 4096 total
    const ushort4 a = ks[idx];
    const ushort4 c = vs[idx];
    *reinterpret_cast<float4*>(&kls[idx * 4]) =
        make_float4(bf2f(a.x), bf2f(a.y), bf2f(a.z), bf2f(a.w));
    *reinterpret_cast<float4*>(&vls[idx * 4]) =
        make_float4(bf2f(c.x), bf2f(c.y), bf2f(c.z), bf2f(c.w));
  }

  // Load this thread's q row, pre-scaled by 1/sqrt(HS).
  const float scale = 0.125f;
  float qreg[NH];
  {
    const ushort4* q4 = reinterpret_cast<const ushort4*>(qg);
#pragma unroll
    for (int i = 0; i < 16; ++i) {
      const ushort4 a = q4[i];
      qreg[i * 4 + 0] = bf2f(a.x) * scale;
      qreg[i * 4 + 1] = bf2f(a.y) * scale;
      qreg[i * 4 + 2] = bf2f(a.z) * scale;
      qreg[i * 4 + 3] = bf2f(a.w) * scale;
    }
  }

  __syncthreads();

  // Pass 1: running max + sum over s in [0, t].
  float mmax = -INFINITY, lsum = 0.f;
  for (int s = 0; s <= t; ++s) {
    const float* kr = kls + s * NH;
    float d0 = 0.f, d1 = 0.f, d2 = 0.f, d3 = 0.f;
#pragma unroll
    for (int hh = 0; hh < NH; hh += 4) {
      const float4 kv = *reinterpret_cast<const float4*>(kr + hh);
      d0 = fmaf(qreg[hh + 0], kv.x, d0);
      d1 = fmaf(qreg[hh + 1], kv.y, d1);
      d2 = fmaf(qreg[hh + 2], kv.z, d2);
      d3 = fmaf(qreg[hh + 3], kv.w, d3);
    }
    const float dot = (d0 + d1) + (d2 + d3);
    const float nm = fmaxf(mmax, dot);
    lsum = lsum * __expf(mmax - nm) + __expf(dot - nm);
    mmax = nm;
  }
  const float inv_l = 1.f / lsum;

  // Pass 2: recompute scores, accumulate output.
  float o[NH];
#pragma unroll
  for (int hh = 0; hh < NH; ++hh) o[hh] = 0.f;

  for (int s = 0; s <= t; ++s) {
    const float* kr = kls + s * NH;
    const float* vr = vls + s * NH;
    float d0 = 0.f, d1 = 0.f, d2 = 0.f, d3 = 0.f;
#pragma unroll
    for (int hh = 0; hh < NH; hh += 4) {
      const float4 kv = *reinterpret_cast<const float4*>(kr + hh);
      d0 = fmaf(qreg[hh + 0], kv.x, d0);
      d1 = fmaf(qreg[hh + 1], kv.y, d1);
      d2 = fmaf(qreg[hh + 2], kv.z, d2);
      d3 = fmaf(qreg[hh + 3], kv.w, d3);
    }
    const float dot = (d0 + d1) + (d2 + d3);
    const float p = __expf(dot - mmax) * inv_l;
#pragma unroll
    for (int hh = 0; hh < NH; hh += 4) {
      const float4 vv = *reinterpret_cast<const float4*>(vr + hh);
      o[hh + 0] = fmaf(p, vv.x, o[hh + 0]);
      o[hh + 1] = fmaf(p, vv.y, o[hh + 1]);
      o[hh + 2] = fmaf(p, vv.z, o[hh + 2]);
      o[hh + 3] = fmaf(p, vv.w, o[hh + 3]);
    }
  }

  float* og = out + ((size_t)b * NT + t) * NH;
#pragma unroll
  for (int hh = 0; hh < NH; hh += 4) {
    *reinterpret_cast<float4*>(og + hh) =
        make_float4(o[hh + 0], o[hh + 1], o[hh + 2], o[hh + 3]);
  }
}

// ---------------------------------------------------------------------------
extern "C" void kernel_launch(void* const* d_in, const int* in_sizes, int n_in,
                              void* d_out, int out_size, void* d_ws,
                              size_t ws_size, hipStream_t stream) {
  const float* x  = (const float*)d_in[0];
  const float* Wq = (const float*)d_in[1];
  const float* Wk = (const float*)d_in[2];
  const float* Wv = (const float*)d_in[3];
  unsigned short* qkv = (unsigned short*)d_ws;  // 3 * NQ bf16 = 25.2 MB
  float* out = (float*)d_out;

  // Kernel 1: 65536 rows / 128 rows-per-block = 512 blocks.
  qkv_proj_kernel<<<dim3(512), dim3(256), 0, stream>>>(x, Wq, Wk, Wv, qkv);
  // Kernel 2: one block per batch.
  attn_kernel<<<dim3(NB), dim3(256), 0, stream>>>(qkv, out);
}

// Round 2
// 208.135 us; speedup vs baseline: 2.6770x; 2.6770x over previous
//
#include <hip/hip_runtime.h>
#include <hip/hip_bf16.h>

// Problem constants (B, T, C, HS) from the reference.
#define NB 256
#define NT 256
#define NC 384
#define NH 64
#define NQ (NB * NT * NH)  // elements per q/k/v tensor = 4194304

typedef short bf16x8 __attribute__((ext_vector_type(8)));
typedef float f32x4 __attribute__((ext_vector_type(4)));

__device__ __forceinline__ float bf2f(unsigned short u) {
  union { unsigned int i; float f; } c;
  c.i = ((unsigned int)u) << 16;
  return c.f;
}

__device__ __forceinline__ unsigned short f2bf(float f) {
  union { float f; unsigned int i; } c;
  c.f = f;
  const unsigned int r = c.i + 0x7fffu + ((c.i >> 16) & 1u);
  return (unsigned short)(r >> 16);
}

// ---------------------------------------------------------------------------
// Kernel 1: fused QKV projection (unchanged from round 1 — isolate attn edit).
// ---------------------------------------------------------------------------
__global__ __launch_bounds__(256) void qkv_proj_kernel(
    const float* __restrict__ x,
    const float* __restrict__ Wq,
    const float* __restrict__ Wk,
    const float* __restrict__ Wv,
    unsigned short* __restrict__ qkv) {
  const int hp = threadIdx.x & 31;
  const int g  = threadIdx.x >> 5;
  const int row0 = blockIdx.x * 128 + g * 16;

  float aq[16][2], ak[16][2], av[16][2];
#pragma unroll
  for (int i = 0; i < 16; ++i) {
    aq[i][0] = aq[i][1] = 0.f;
    ak[i][0] = ak[i][1] = 0.f;
    av[i][0] = av[i][1] = 0.f;
  }

  const float* xr = x + (size_t)row0 * NC;

  for (int c = 0; c < NC; c += 4) {
    float2 wq[4], wk[4], wv[4];
#pragma unroll
    for (int j = 0; j < 4; ++j) {
      wq[j] = *reinterpret_cast<const float2*>(Wq + (c + j) * NH + hp * 2);
      wk[j] = *reinterpret_cast<const float2*>(Wk + (c + j) * NH + hp * 2);
      wv[j] = *reinterpret_cast<const float2*>(Wv + (c + j) * NH + hp * 2);
    }
#pragma unroll
    for (int i = 0; i < 16; ++i) {
      const float4 xv = *reinterpret_cast<const float4*>(xr + i * NC + c);
      aq[i][0] = fmaf(xv.x, wq[0].x, aq[i][0]);
      aq[i][0] = fmaf(xv.y, wq[1].x, aq[i][0]);
      aq[i][0] = fmaf(xv.z, wq[2].x, aq[i][0]);
      aq[i][0] = fmaf(xv.w, wq[3].x, aq[i][0]);
      aq[i][1] = fmaf(xv.x, wq[0].y, aq[i][1]);
      aq[i][1] = fmaf(xv.y, wq[1].y, aq[i][1]);
      aq[i][1] = fmaf(xv.z, wq[2].y, aq[i][1]);
      aq[i][1] = fmaf(xv.w, wq[3].y, aq[i][1]);

      ak[i][0] = fmaf(xv.x, wk[0].x, ak[i][0]);
      ak[i][0] = fmaf(xv.y, wk[1].x, ak[i][0]);
      ak[i][0] = fmaf(xv.z, wk[2].x, ak[i][0]);
      ak[i][0] = fmaf(xv.w, wk[3].x, ak[i][0]);
      ak[i][1] = fmaf(xv.x, wk[0].y, ak[i][1]);
      ak[i][1] = fmaf(xv.y, wk[1].y, ak[i][1]);
      ak[i][1] = fmaf(xv.z, wk[2].y, ak[i][1]);
      ak[i][1] = fmaf(xv.w, wk[3].y, ak[i][1]);

      av[i][0] = fmaf(xv.x, wv[0].x, av[i][0]);
      av[i][0] = fmaf(xv.y, wv[1].x, av[i][0]);
      av[i][0] = fmaf(xv.z, wv[2].x, av[i][0]);
      av[i][0] = fmaf(xv.w, wv[3].x, av[i][0]);
      av[i][1] = fmaf(xv.x, wv[0].y, av[i][1]);
      av[i][1] = fmaf(xv.y, wv[1].y, av[i][1]);
      av[i][1] = fmaf(xv.z, wv[2].y, av[i][1]);
      av[i][1] = fmaf(xv.w, wv[3].y, av[i][1]);
    }
  }

#pragma unroll
  for (int i = 0; i < 16; ++i) {
    const size_t ro = (size_t)(row0 + i) * NH + hp * 2;
    ushort2 s;
    s.x = f2bf(aq[i][0]); s.y = f2bf(aq[i][1]);
    *reinterpret_cast<ushort2*>(qkv + ro) = s;
    s.x = f2bf(ak[i][0]); s.y = f2bf(ak[i][1]);
    *reinterpret_cast<ushort2*>(qkv + NQ + ro) = s;
    s.x = f2bf(av[i][0]); s.y = f2bf(av[i][1]);
    *reinterpret_cast<ushort2*>(qkv + 2 * NQ + ro) = s;
  }
}

// ---------------------------------------------------------------------------
// Kernel 2: MFMA causal flash attention. One block (512 thr = 8 waves) per
// batch. Wave w owns Q-tile (w<4 ? w : 11-w)*32 rows, so each SIMD's two
// waves (w, w+4) have equal causal work.
//
// mfma_f32_16x16x32_bf16 layouts (guide §3, m89-verified C/D; A/B standard
// CDNA contiguous-k):
//   A[m][k]: lane l holds m = l&15,        k = (l>>4)*8 + j   (8 bf16, b128)
//   B[k][n]: lane l holds n = l&15,        k = (l>>4)*8 + j
//   D[m][n]: lane l holds n = l&15,        m = (l>>4)*4 + reg
//
// K in LDS row-major [256][64] bf16, XOR-swizzled (el ^= (row&7)<<3) to kill
// the 16-way bank conflict of 128B-stride b128 reads (T2 / G4).
// V in LDS transposed [64][256] bf16, same swizzle, so PV's B-fragment is
// contiguous in k.
// P bounced through per-wave LDS [32][40] bf16 (pad to 40 -> balanced banks)
// to convert the D-layout into the PV A-fragment layout.
// One __syncthreads after staging; waves independent afterwards.
// ---------------------------------------------------------------------------
__global__ __launch_bounds__(512) void attn_mfma_kernel(
    const unsigned short* __restrict__ qkv,
    float* __restrict__ out) {
  __shared__ unsigned short Kls[NT * NH];        // 32 KB, swizzled rows 128B
  __shared__ unsigned short Vtls[NH * NT];       // 32 KB, swizzled rows 512B
  __shared__ unsigned short Pls[8][32 * 40];     // 20 KB, per-wave P tile

  const int b = blockIdx.x;
  const int tid = threadIdx.x;
  const int w = tid >> 6;
  const int lane = tid & 63;
  const int l15 = lane & 15;
  const int lg = lane >> 4;  // 0..3

  const unsigned short* Qg = qkv + (size_t)b * NT * NH;
  const unsigned short* Kg = Qg + NQ;
  const unsigned short* Vg = Qg + 2 * NQ;

  // ---- stage K (swizzled row-major) ----
#pragma unroll
  for (int it = 0; it < 4; ++it) {
    const int idx = it * 512 + tid;        // 0..2047 chunks of 8 elems
    const int row = idx >> 3, ch = idx & 7;
    *reinterpret_cast<uint4*>(&Kls[row * 64 + ((ch * 8) ^ ((row & 7) << 3))]) =
        *reinterpret_cast<const uint4*>(Kg + row * 64 + ch * 8);
  }
  // ---- stage V transposed (swizzled) ----
  {
    const int s = tid & 255, hq = tid >> 8;  // hq in {0,1}
#pragma unroll
    for (int c = 0; c < 4; ++c) {
      unsigned short va[8];
      *reinterpret_cast<uint4*>(va) =
          *reinterpret_cast<const uint4*>(Vg + s * 64 + hq * 32 + c * 8);
#pragma unroll
      for (int i = 0; i < 8; ++i) {
        const int h = hq * 32 + c * 8 + i;
        Vtls[h * 256 + (s ^ ((h & 7) << 3))] = va[i];
      }
    }
  }
  __syncthreads();

  const int qt = (w < 4) ? w : 11 - w;  // per-SIMD balanced causal tiles
  const int q0 = qt * 32;

  // ---- Q fragments (from global, once) ----
  bf16x8 a_q[2][2];
#pragma unroll
  for (int mi = 0; mi < 2; ++mi)
#pragma unroll
    for (int ks = 0; ks < 2; ++ks)
      a_q[mi][ks] = *reinterpret_cast<const bf16x8*>(
          Qg + (q0 + mi * 16 + l15) * 64 + ks * 32 + lg * 8);

  f32x4 o[2][4];
  float mrun[2][4], lrun[2][4];
#pragma unroll
  for (int mi = 0; mi < 2; ++mi)
#pragma unroll
    for (int r = 0; r < 4; ++r) {
      mrun[mi][r] = -3.0e38f;
      lrun[mi][r] = 0.f;
#pragma unroll
      for (int hi = 0; hi < 4; ++hi) o[mi][hi][r] = 0.f;
    }

  for (int j = 0; j <= qt; ++j) {
    // ---- S = Q K^T (32x32) ----
    f32x4 s_acc[2][2];
#pragma unroll
    for (int mi = 0; mi < 2; ++mi)
#pragma unroll
      for (int si = 0; si < 2; ++si)
#pragma unroll
        for (int r = 0; r < 4; ++r) s_acc[mi][si][r] = 0.f;

#pragma unroll
    for (int ks = 0; ks < 2; ++ks) {
      bf16x8 bk[2];
#pragma unroll
      for (int si = 0; si < 2; ++si) {
        const int srow = j * 32 + si * 16 + l15;
        const int kel = ks * 32 + lg * 8;
        bk[si] = *reinterpret_cast<const bf16x8*>(
            &Kls[srow * 64 + (kel ^ ((srow & 7) << 3))]);
      }
#pragma unroll
      for (int mi = 0; mi < 2; ++mi)
#pragma unroll
        for (int si = 0; si < 2; ++si)
          s_acc[mi][si] = __builtin_amdgcn_mfma_f32_16x16x32_bf16(
              a_q[mi][ks], bk[si], s_acc[mi][si], 0, 0, 0);
    }

    // ---- online softmax on S rows (row = mi*16 + lg*4 + r, col = l15+16si)
    const bool diag = (j == qt);
#pragma unroll
    for (int mi = 0; mi < 2; ++mi) {
#pragma unroll
      for (int r = 0; r < 4; ++r) {
        const int mloc = mi * 16 + lg * 4 + r;
        float v0 = s_acc[mi][0][r] * 0.125f;
        float v1 = s_acc[mi][1][r] * 0.125f;
        if (diag) {
          if (l15 > mloc) v0 = -3.0e38f;
          if (16 + l15 > mloc) v1 = -3.0e38f;
        }
        float pm = fmaxf(v0, v1);
        pm = fmaxf(pm, __shfl_xor(pm, 1, 16));
        pm = fmaxf(pm, __shfl_xor(pm, 2, 16));
        pm = fmaxf(pm, __shfl_xor(pm, 4, 16));
        pm = fmaxf(pm, __shfl_xor(pm, 8, 16));
        const float mnew = fmaxf(mrun[mi][r], pm);
        const float alpha = __expf(mrun[mi][r] - mnew);
        mrun[mi][r] = mnew;
        const float p0 = __expf(v0 - mnew);
        const float p1 = __expf(v1 - mnew);
        float ps = p0 + p1;
        ps += __shfl_xor(ps, 1, 16);
        ps += __shfl_xor(ps, 2, 16);
        ps += __shfl_xor(ps, 4, 16);
        ps += __shfl_xor(ps, 8, 16);
        lrun[mi][r] = lrun[mi][r] * alpha + ps;
#pragma unroll
        for (int hi = 0; hi < 4; ++hi) o[mi][hi][r] *= alpha;
        Pls[w][mloc * 40 + l15] = f2bf(p0);
        Pls[w][mloc * 40 + 16 + l15] = f2bf(p1);
      }
    }

    // ---- O += P V ----
    bf16x8 pa[2];
#pragma unroll
    for (int mt = 0; mt < 2; ++mt)
      pa[mt] = *reinterpret_cast<const bf16x8*>(
          &Pls[w][(mt * 16 + l15) * 40 + lg * 8]);
#pragma unroll
    for (int hi = 0; hi < 4; ++hi) {
      const int h = hi * 16 + l15;
      const int sel = j * 32 + lg * 8;
      const bf16x8 bv = *reinterpret_cast<const bf16x8*>(
          &Vtls[h * 256 + (sel ^ ((h & 7) << 3))]);
#pragma unroll
      for (int mt = 0; mt < 2; ++mt)
        o[mt][hi] = __builtin_amdgcn_mfma_f32_16x16x32_bf16(
            pa[mt], bv, o[mt][hi], 0, 0, 0);
    }
  }

  // ---- epilogue: normalize and store ----
  float* og = out + ((size_t)b * NT + q0) * NH;
#pragma unroll
  for (int mi = 0; mi < 2; ++mi)
#pragma unroll
    for (int r = 0; r < 4; ++r) {
      const float inv = 1.f / lrun[mi][r];
      const int m = mi * 16 + lg * 4 + r;
#pragma unroll
      for (int hi = 0; hi < 4; ++hi)
        og[m * 64 + hi * 16 + l15] = o[mi][hi][r] * inv;
    }
}

// ---------------------------------------------------------------------------
extern "C" void kernel_launch(void* const* d_in, const int* in_sizes, int n_in,
                              void* d_out, int out_size, void* d_ws,
                              size_t ws_size, hipStream_t stream) {
  const float* x  = (const float*)d_in[0];
  const float* Wq = (const float*)d_in[1];
  const float* Wk = (const float*)d_in[2];
  const float* Wv = (const float*)d_in[3];
  unsigned short* qkv = (unsigned short*)d_ws;  // 3 * NQ bf16 = 25.2 MB
  float* out = (float*)d_out;

  qkv_proj_kernel<<<dim3(512), dim3(256), 0, stream>>>(x, Wq, Wk, Wv, qkv);
  attn_mfma_kernel<<<dim3(NB), dim3(512), 0, stream>>>(qkv, out);
}

// Round 3
// 84.358 us; speedup vs baseline: 6.6049x; 2.4673x over previous
//
#include <hip/hip_runtime.h>
#include <hip/hip_bf16.h>

// Problem constants (B, T, C, HS) from the reference.
#define NB 256
#define NT 256
#define NC 384
#define NH 64
#define NQ (NB * NT * NH)   // elements per q/k/v tensor = 4194304
#define NW 192              // 3 * NH concatenated output cols
#define WT_ELEMS (NW * NC)  // Wt bf16 elements = 73728

typedef short bf16x8 __attribute__((ext_vector_type(8)));
typedef float f32x4 __attribute__((ext_vector_type(4)));

__device__ __forceinline__ float bf2f(unsigned short u) {
  union { unsigned int i; float f; } c;
  c.i = ((unsigned int)u) << 16;
  return c.f;
}

__device__ __forceinline__ unsigned short f2bf(float f) {
  union { float f; unsigned int i; } c;
  c.f = f;
  const unsigned int r = c.i + 0x7fffu + ((c.i >> 16) & 1u);
  return (unsigned short)(r >> 16);
}

// ---------------------------------------------------------------------------
// Kernel 0: transpose + convert weights.
// Wt[n][k] (bf16, [192][384]) = W{q,k,v}[k][n%64], n<64:q, <128:k, <192:v.
// 73728 elements; trivial one-shot prep so both GEMM operands become
// contiguous-in-k 16B fragment loads.
// ---------------------------------------------------------------------------
__global__ __launch_bounds__(256) void w_transpose_kernel(
    const float* __restrict__ Wq,
    const float* __restrict__ Wk,
    const float* __restrict__ Wv,
    unsigned short* __restrict__ Wt) {
  const int idx = blockIdx.x * 256 + threadIdx.x;  // 288 blocks
  if (idx >= WT_ELEMS) return;
  const int n = idx / NC, k = idx - n * NC;
  const float* W = (n < 64) ? Wq : (n < 128) ? Wk : Wv;
  Wt[idx] = f2bf(W[k * NH + (n & 63)]);
}

// ---------------------------------------------------------------------------
// Kernel 1: fused QKV projection via MFMA.
//   [65536 x 384] (x, fp32->bf16 inline) @ [384 x 192] (Wt) -> qkv bf16.
// Block = 256 thr = 4 waves; wave owns 32 rows x all 192 cols.
// A-frags: float8 from x, cvt to bf16 in-register (x read exactly once,
// streaming, 64B-coalesced). B-frags: b128 from Wt (147 KB, L1/L2-resident,
// shared by all blocks). acc = 2x12 f32x4 = 96 VGPR. No LDS.
// mfma_f32_16x16x32_bf16 layouts (HW-verified in round 2):
//   A/B: k = (l>>4)*8+j contiguous;  D: n = l&15, m = (l>>4)*4 + r.
// ---------------------------------------------------------------------------
__global__ __launch_bounds__(256) void qkv_proj_mfma(
    const float* __restrict__ x,
    const unsigned short* __restrict__ Wt,
    unsigned short* __restrict__ qkv) {
  const int w = threadIdx.x >> 6;
  const int lane = threadIdx.x & 63;
  const int l15 = lane & 15;
  const int lg = lane >> 4;
  const int row0 = blockIdx.x * 128 + w * 32;

  f32x4 acc[2][12];
#pragma unroll
  for (int mi = 0; mi < 2; ++mi)
#pragma unroll
    for (int ni = 0; ni < 12; ++ni)
#pragma unroll
      for (int r = 0; r < 4; ++r) acc[mi][ni][r] = 0.f;

#pragma unroll 2
  for (int kt = 0; kt < 12; ++kt) {
    // A fragments: 8 consecutive fp32 of x -> bf16x8.
    bf16x8 a[2];
#pragma unroll
    for (int mi = 0; mi < 2; ++mi) {
      const float* xp =
          x + (size_t)(row0 + mi * 16 + l15) * NC + kt * 32 + lg * 8;
      const float4 x0 = *reinterpret_cast<const float4*>(xp);
      const float4 x1 = *reinterpret_cast<const float4*>(xp + 4);
      a[mi][0] = (short)f2bf(x0.x);
      a[mi][1] = (short)f2bf(x0.y);
      a[mi][2] = (short)f2bf(x0.z);
      a[mi][3] = (short)f2bf(x0.w);
      a[mi][4] = (short)f2bf(x1.x);
      a[mi][5] = (short)f2bf(x1.y);
      a[mi][6] = (short)f2bf(x1.z);
      a[mi][7] = (short)f2bf(x1.w);
    }
    // B fragments from Wt (row n, contiguous k) + MFMA.
#pragma unroll
    for (int ni = 0; ni < 12; ++ni) {
      const bf16x8 bfrag = *reinterpret_cast<const bf16x8*>(
          Wt + (size_t)(ni * 16 + l15) * NC + kt * 32 + lg * 8);
      acc[0][ni] = __builtin_amdgcn_mfma_f32_16x16x32_bf16(
          a[0], bfrag, acc[0][ni], 0, 0, 0);
      acc[1][ni] = __builtin_amdgcn_mfma_f32_16x16x32_bf16(
          a[1], bfrag, acc[1][ni], 0, 0, 0);
    }
  }

  // Store: lane holds col n = ni*16+l15, rows m = lg*4+r (per verified D).
#pragma unroll
  for (int mi = 0; mi < 2; ++mi)
#pragma unroll
    for (int ni = 0; ni < 12; ++ni) {
      const int n = ni * 16 + l15;
      unsigned short* dst = qkv + (size_t)(n >> 6) * NQ + (n & 63);
#pragma unroll
      for (int r = 0; r < 4; ++r) {
        const int grow = row0 + mi * 16 + lg * 4 + r;
        dst[(size_t)grow * NH] = f2bf(acc[mi][ni][r]);
      }
    }
}

// ---------------------------------------------------------------------------
// Kernel 2: MFMA causal flash attention (unchanged from round 2).
// ---------------------------------------------------------------------------
__global__ __launch_bounds__(512) void attn_mfma_kernel(
    const unsigned short* __restrict__ qkv,
    float* __restrict__ out) {
  __shared__ unsigned short Kls[NT * NH];
  __shared__ unsigned short Vtls[NH * NT];
  __shared__ unsigned short Pls[8][32 * 40];

  const int b = blockIdx.x;
  const int tid = threadIdx.x;
  const int w = tid >> 6;
  const int lane = tid & 63;
  const int l15 = lane & 15;
  const int lg = lane >> 4;

  const unsigned short* Qg = qkv + (size_t)b * NT * NH;
  const unsigned short* Kg = Qg + NQ;
  const unsigned short* Vg = Qg + 2 * NQ;

#pragma unroll
  for (int it = 0; it < 4; ++it) {
    const int idx = it * 512 + tid;
    const int row = idx >> 3, ch = idx & 7;
    *reinterpret_cast<uint4*>(&Kls[row * 64 + ((ch * 8) ^ ((row & 7) << 3))]) =
        *reinterpret_cast<const uint4*>(Kg + row * 64 + ch * 8);
  }
  {
    const int s = tid & 255, hq = tid >> 8;
#pragma unroll
    for (int c = 0; c < 4; ++c) {
      unsigned short va[8];
      *reinterpret_cast<uint4*>(va) =
          *reinterpret_cast<const uint4*>(Vg + s * 64 + hq * 32 + c * 8);
#pragma unroll
      for (int i = 0; i < 8; ++i) {
        const int h = hq * 32 + c * 8 + i;
        Vtls[h * 256 + (s ^ ((h & 7) << 3))] = va[i];
      }
    }
  }
  __syncthreads();

  const int qt = (w < 4) ? w : 11 - w;
  const int q0 = qt * 32;

  bf16x8 a_q[2][2];
#pragma unroll
  for (int mi = 0; mi < 2; ++mi)
#pragma unroll
    for (int ks = 0; ks < 2; ++ks)
      a_q[mi][ks] = *reinterpret_cast<const bf16x8*>(
          Qg + (q0 + mi * 16 + l15) * 64 + ks * 32 + lg * 8);

  f32x4 o[2][4];
  float mrun[2][4], lrun[2][4];
#pragma unroll
  for (int mi = 0; mi < 2; ++mi)
#pragma unroll
    for (int r = 0; r < 4; ++r) {
      mrun[mi][r] = -3.0e38f;
      lrun[mi][r] = 0.f;
#pragma unroll
      for (int hi = 0; hi < 4; ++hi) o[mi][hi][r] = 0.f;
    }

  for (int j = 0; j <= qt; ++j) {
    f32x4 s_acc[2][2];
#pragma unroll
    for (int mi = 0; mi < 2; ++mi)
#pragma unroll
      for (int si = 0; si < 2; ++si)
#pragma unroll
        for (int r = 0; r < 4; ++r) s_acc[mi][si][r] = 0.f;

#pragma unroll
    for (int ks = 0; ks < 2; ++ks) {
      bf16x8 bk[2];
#pragma unroll
      for (int si = 0; si < 2; ++si) {
        const int srow = j * 32 + si * 16 + l15;
        const int kel = ks * 32 + lg * 8;
        bk[si] = *reinterpret_cast<const bf16x8*>(
            &Kls[srow * 64 + (kel ^ ((srow & 7) << 3))]);
      }
#pragma unroll
      for (int mi = 0; mi < 2; ++mi)
#pragma unroll
        for (int si = 0; si < 2; ++si)
          s_acc[mi][si] = __builtin_amdgcn_mfma_f32_16x16x32_bf16(
              a_q[mi][ks], bk[si], s_acc[mi][si], 0, 0, 0);
    }

    const bool diag = (j == qt);
#pragma unroll
    for (int mi = 0; mi < 2; ++mi) {
#pragma unroll
      for (int r = 0; r < 4; ++r) {
        const int mloc = mi * 16 + lg * 4 + r;
        float v0 = s_acc[mi][0][r] * 0.125f;
        float v1 = s_acc[mi][1][r] * 0.125f;
        if (diag) {
          if (l15 > mloc) v0 = -3.0e38f;
          if (16 + l15 > mloc) v1 = -3.0e38f;
        }
        float pm = fmaxf(v0, v1);
        pm = fmaxf(pm, __shfl_xor(pm, 1, 16));
        pm = fmaxf(pm, __shfl_xor(pm, 2, 16));
        pm = fmaxf(pm, __shfl_xor(pm, 4, 16));
        pm = fmaxf(pm, __shfl_xor(pm, 8, 16));
        const float mnew = fmaxf(mrun[mi][r], pm);
        const float alpha = __expf(mrun[mi][r] - mnew);
        mrun[mi][r] = mnew;
        const float p0 = __expf(v0 - mnew);
        const float p1 = __expf(v1 - mnew);
        float ps = p0 + p1;
        ps += __shfl_xor(ps, 1, 16);
        ps += __shfl_xor(ps, 2, 16);
        ps += __shfl_xor(ps, 4, 16);
        ps += __shfl_xor(ps, 8, 16);
        lrun[mi][r] = lrun[mi][r] * alpha + ps;
#pragma unroll
        for (int hi = 0; hi < 4; ++hi) o[mi][hi][r] *= alpha;
        Pls[w][mloc * 40 + l15] = f2bf(p0);
        Pls[w][mloc * 40 + 16 + l15] = f2bf(p1);
      }
    }

    bf16x8 pa[2];
#pragma unroll
    for (int mt = 0; mt < 2; ++mt)
      pa[mt] = *reinterpret_cast<const bf16x8*>(
          &Pls[w][(mt * 16 + l15) * 40 + lg * 8]);
#pragma unroll
    for (int hi = 0; hi < 4; ++hi) {
      const int h = hi * 16 + l15;
      const int sel = j * 32 + lg * 8;
      const bf16x8 bv = *reinterpret_cast<const bf16x8*>(
          &Vtls[h * 256 + (sel ^ ((h & 7) << 3))]);
#pragma unroll
      for (int mt = 0; mt < 2; ++mt)
        o[mt][hi] = __builtin_amdgcn_mfma_f32_16x16x32_bf16(
            pa[mt], bv, o[mt][hi], 0, 0, 0);
    }
  }

  float* og = out + ((size_t)b * NT + q0) * NH;
#pragma unroll
  for (int mi = 0; mi < 2; ++mi)
#pragma unroll
    for (int r = 0; r < 4; ++r) {
      const float inv = 1.f / lrun[mi][r];
      const int m = mi * 16 + lg * 4 + r;
#pragma unroll
      for (int hi = 0; hi < 4; ++hi)
        og[m * 64 + hi * 16 + l15] = o[mi][hi][r] * inv;
    }
}

// ---------------------------------------------------------------------------
extern "C" void kernel_launch(void* const* d_in, const int* in_sizes, int n_in,
                              void* d_out, int out_size, void* d_ws,
                              size_t ws_size, hipStream_t stream) {
  const float* x  = (const float*)d_in[0];
  const float* Wq = (const float*)d_in[1];
  const float* Wk = (const float*)d_in[2];
  const float* Wv = (const float*)d_in[3];
  unsigned short* Wt  = (unsigned short*)d_ws;            // 147 KB
  unsigned short* qkv = (unsigned short*)d_ws + WT_ELEMS; // 25.2 MB
  float* out = (float*)d_out;

  w_transpose_kernel<<<dim3((WT_ELEMS + 255) / 256), dim3(256), 0, stream>>>(
      Wq, Wk, Wv, Wt);
  qkv_proj_mfma<<<dim3(512), dim3(256), 0, stream>>>(x, Wt, qkv);
  attn_mfma_kernel<<<dim3(NB), dim3(512), 0, stream>>>(qkv, out);
}